// Round 16
// baseline (217.656 us; speedup 1.0000x reference)
//
#include <hip/hip_runtime.h>
#include <hip/hip_fp16.h>
#include <math.h>

#define HID 128

typedef _Float16 half8 __attribute__((ext_vector_type(8)));
typedef float floatx4 __attribute__((ext_vector_type(4)));

// 8-byte packed 4x fp16
struct h4pack { __half2 a, b; };

__device__ __forceinline__ float4 h4tof4(h4pack h) {
  float2 lo = __half22float2(h.a);
  float2 hi = __half22float2(h.b);
  return make_float4(lo.x, lo.y, hi.x, hi.y);
}

__device__ __forceinline__ h4pack f4toh4(float4 v) {
  h4pack h;
  h.a = __floats2half2_rn(v.x, v.y);
  h.b = __floats2half2_rn(v.z, v.w);
  return h;
}

// ---------------- zero workspace --------------------------------------------
__global__ __launch_bounds__(256) void zero_kernel(int4* __restrict__ p, int n4) {
  int i = blockIdx.x * 256 + threadIdx.x;
  if (i < n4) p[i] = make_int4(0, 0, 0, 0);
}

// ---------------- CSR build (padded to 8-edge octets) ------------------------
__global__ __launch_bounds__(256) void hist_kernel(
    const int* __restrict__ dst, int* __restrict__ counts,
    int* __restrict__ rank, int E) {
  int e = blockIdx.x * 256 + threadIdx.x;
  if (e < E) rank[e] = atomicAdd(&counts[dst[e]], 1);
}

__global__ __launch_bounds__(256) void partial_kernel(
    const int* __restrict__ counts, int* __restrict__ partials, int N) {
  __shared__ int s[256];
  int idx = blockIdx.x * 256 + threadIdx.x;
  int c = (idx < N) ? counts[idx] : 0;
  s[threadIdx.x] = (idx < N) ? ((c + 7) & ~7) : 0;
  __syncthreads();
  for (int o = 128; o > 0; o >>= 1) {
    if (threadIdx.x < o) s[threadIdx.x] += s[threadIdx.x + o];
    __syncthreads();
  }
  if (threadIdx.x == 0) partials[blockIdx.x] = s[0];
}

__global__ __launch_bounds__(256) void scan2_kernel(
    const int* __restrict__ partials, int* __restrict__ bases, int NB) {
  __shared__ int s[256];
  int t = threadIdx.x;
  int v0 = (t < NB) ? partials[t] : 0;
  s[t] = v0;
  __syncthreads();
  for (int o = 1; o < 256; o <<= 1) {
    int v = (t >= o) ? s[t - o] : 0;
    __syncthreads();
    s[t] += v;
    __syncthreads();
  }
  bases[t] = s[t] - v0;   // exclusive
}

__global__ __launch_bounds__(256) void offs_kernel(
    const int* __restrict__ counts, const int* __restrict__ bases,
    int* __restrict__ offs, int* __restrict__ csr, int N) {
  __shared__ int s[256];
  int t = threadIdx.x;
  int idx = blockIdx.x * 256 + t;
  int deg = (idx < N) ? counts[idx] : 0;
  int c = (idx < N) ? ((deg + 7) & ~7) : 0;
  s[t] = c;
  __syncthreads();
  for (int o = 1; o < 256; o <<= 1) {
    int v = (t >= o) ? s[t - o] : 0;
    __syncthreads();
    s[t] += v;
    __syncthreads();
  }
  int base = bases[blockIdx.x];
  if (idx < N) {
    int o = base + s[t] - c;
    offs[idx] = o;
    for (int k = deg; k < c; ++k) csr[o + k] = 0;
  }
  if (idx == N - 1) offs[N] = base + s[t];
}

__global__ __launch_bounds__(256) void scatter_kernel(
    const int* __restrict__ src, const int* __restrict__ dst,
    const int* __restrict__ offs, const int* __restrict__ rank,
    int* __restrict__ csr, int E) {
  int e = blockIdx.x * 256 + threadIdx.x;
  if (e >= E) return;
  csr[offs[dst[e]] + rank[e]] = src[e];
}

// ---------------- embed: h0 = relu(ke[f0]+ve[f1]) -> fp16 -------------------
__global__ __launch_bounds__(256) void embed_kernel(
    const int* __restrict__ feats, const float* __restrict__ ke,
    const float* __restrict__ ve, __half* __restrict__ h0, int N) {
  int gid = blockIdx.x * 256 + threadIdx.x;
  int n = gid >> 4, j = gid & 15;     // 16 threads/node, 8 dims each
  if (n >= N) return;
  int f0 = feats[2 * n], f1 = feats[2 * n + 1];
  const float4* a4 = (const float4*)(ke + (size_t)f0 * HID) + j * 2;
  const float4* b4 = (const float4*)(ve + (size_t)f1 * HID) + j * 2;
  float4 a0 = a4[0], a1 = a4[1], b0 = b4[0], b1 = b4[1];
  float4 v0, v1;
  v0.x = fmaxf(a0.x + b0.x, 0.f); v0.y = fmaxf(a0.y + b0.y, 0.f);
  v0.z = fmaxf(a0.z + b0.z, 0.f); v0.w = fmaxf(a0.w + b0.w, 0.f);
  v1.x = fmaxf(a1.x + b1.x, 0.f); v1.y = fmaxf(a1.y + b1.y, 0.f);
  v1.z = fmaxf(a1.z + b1.z, 0.f); v1.w = fmaxf(a1.w + b1.w, 0.f);
  h4pack* out = (h4pack*)h0 + (size_t)n * 32 + j * 2;
  out[0] = f4toh4(v0);
  out[1] = f4toh4(v1);
}

// ---------------- W prep: Wt[c][k] = fp16(W[k][c]) --------------------------
__global__ __launch_bounds__(256) void wprep_kernel(
    const float* __restrict__ W, __half* __restrict__ Wt) {
  int t = blockIdx.x * 256 + threadIdx.x;   // 16384
  int k = t >> 7, c = t & 127;
  Wt[(size_t)c * HID + k] = __float2half(W[t]);
}

// ---------------- GEMM via MFMA: F[N,128](fp16) = A[N,128](fp16) @ W --------
__global__ __launch_bounds__(256) void gemm_mfma_kernel(
    const __half* __restrict__ A, const __half* __restrict__ Wt,
    __half* __restrict__ F, int N) {
  int w = threadIdx.x >> 6;
  int lane = threadIdx.x & 63;
  int r = lane & 15, g = lane >> 4;
  int row0 = blockIdx.x * 64 + w * 16;
  if (row0 >= N) return;
  int arow = row0 + r;
  if (arow >= N) arow = N - 1;        // clamp (stores are guarded)
  const half8* Ap = (const half8*)(A + (size_t)arow * HID + g * 8);
  half8 a0 = Ap[0];                    // k =   0 + g*8
  half8 a1 = Ap[4];                    // k =  32 + g*8
  half8 a2 = Ap[8];                    // k =  64 + g*8
  half8 a3 = Ap[12];                   // k =  96 + g*8
#pragma unroll
  for (int ct = 0; ct < 8; ++ct) {
    const half8* Bp = (const half8*)(Wt + (size_t)(ct * 16 + r) * HID + g * 8);
    half8 b0 = Bp[0], b1 = Bp[4], b2 = Bp[8], b3 = Bp[12];
    floatx4 c = {0.f, 0.f, 0.f, 0.f};
    c = __builtin_amdgcn_mfma_f32_16x16x32_f16(a0, b0, c, 0, 0, 0);
    c = __builtin_amdgcn_mfma_f32_16x16x32_f16(a1, b1, c, 0, 0, 0);
    c = __builtin_amdgcn_mfma_f32_16x16x32_f16(a2, b2, c, 0, 0, 0);
    c = __builtin_amdgcn_mfma_f32_16x16x32_f16(a3, b3, c, 0, 0, 0);
    int col = ct * 16 + r;
#pragma unroll
    for (int reg = 0; reg < 4; ++reg) {
      int row = row0 + g * 4 + reg;
      if (row < N) F[(size_t)row * HID + col] = __float2half(c[reg]);
    }
  }
}

// ---------------- GATv2 layer (8-wide, no-max, fp16 in/out, grid-stride) ----
// 32-lane group = 1 node; 2048 blocks (8/CU resident) sweep nodes in strides
// of 8*gridDim so each block does several node-sets (amortizes launch front).
// All shuffles use masks <=16 (within-group); bpermute uses own-group base ->
// inter-group divergence on the sweep loop is safe.
__device__ __forceinline__ float dot4f(const float4& f, const float4& fd,
                                       const float4& a6, const float4& a4) {
  float t, p;
  t = f.x + fd.x; p = a6.x * t;         p = fmaf(a4.x, fabsf(t), p);
  t = f.y + fd.y; p = fmaf(a6.y, t, p); p = fmaf(a4.y, fabsf(t), p);
  t = f.z + fd.z; p = fmaf(a6.z, t, p); p = fmaf(a4.z, fabsf(t), p);
  t = f.w + fd.w; p = fmaf(a6.w, t, p); p = fmaf(a4.w, fabsf(t), p);
  return p;
}

__global__ __launch_bounds__(256) void gat_kernel(
    const __half* __restrict__ F, const int* __restrict__ offs,
    const int* __restrict__ counts, const int* __restrict__ csr,
    const float* __restrict__ attn, __half* __restrict__ Hout, int N) {
  int q = threadIdx.x & 31;
  int lane = threadIdx.x & 63;
  const h4pack* F4h = (const h4pack*)F;
  float4 av = ((const float4*)attn)[q];
  float4 a6, a4;
  a6.x = 0.6f * av.x; a6.y = 0.6f * av.y; a6.z = 0.6f * av.z; a6.w = 0.6f * av.w;
  a4.x = 0.4f * av.x; a4.y = 0.4f * av.y; a4.z = 0.4f * av.z; a4.w = 0.4f * av.w;
  int ib = (lane & 32) << 2;          // bpermute byte base of this group
  bool b1 = (q & 1) != 0;
  bool b2 = (q & 2) != 0;
  bool b4 = (q & 4) != 0;
  int stride = gridDim.x * 8;

  for (int node = blockIdx.x * 8 + (threadIdx.x >> 5); node < N; node += stride) {
    float4 fd = h4tof4(F4h[(size_t)node * 32 + q]);
    int beg = offs[node];
    int cnt = counts[node];
    float l = 0.f;
    float4 acc = make_float4(0.f, 0.f, 0.f, 0.f);

    int nit = (cnt + 7) >> 3;
    const int* cp = csr + beg;        // beg multiple of 8 -> 32B aligned
    for (int it = 0; it < nit; ++it) {
      const int4* qp = (const int4*)(cp + 8 * it);
      int4 sa = qp[0];
      int4 sb = qp[1];
      float4 fa0 = h4tof4(F4h[(size_t)sa.x * 32 + q]);
      float4 fa1 = h4tof4(F4h[(size_t)sa.y * 32 + q]);
      float4 fa2 = h4tof4(F4h[(size_t)sa.z * 32 + q]);
      float4 fa3 = h4tof4(F4h[(size_t)sa.w * 32 + q]);
      float4 fb0 = h4tof4(F4h[(size_t)sb.x * 32 + q]);
      float4 fb1 = h4tof4(F4h[(size_t)sb.y * 32 + q]);
      float4 fb2 = h4tof4(F4h[(size_t)sb.z * 32 + q]);
      float4 fb3 = h4tof4(F4h[(size_t)sb.w * 32 + q]);
      int rem = cnt - 8 * it;
      float p0 = dot4f(fa0, fd, a6, a4);
      float p1 = (1 < rem) ? dot4f(fa1, fd, a6, a4) : -INFINITY;
      float p2 = (2 < rem) ? dot4f(fa2, fd, a6, a4) : -INFINITY;
      float p3 = (3 < rem) ? dot4f(fa3, fd, a6, a4) : -INFINITY;
      float p4 = (4 < rem) ? dot4f(fb0, fd, a6, a4) : -INFINITY;
      float p5 = (5 < rem) ? dot4f(fb1, fd, a6, a4) : -INFINITY;
      float p6 = (6 < rem) ? dot4f(fb2, fd, a6, a4) : -INFINITY;
      float p7 = (7 < rem) ? dot4f(fb3, fd, a6, a4) : -INFINITY;
      float u0 = p0 + __shfl_xor(p0, 1, 64);
      float u1 = p1 + __shfl_xor(p1, 1, 64);
      float u2 = p2 + __shfl_xor(p2, 1, 64);
      float u3 = p3 + __shfl_xor(p3, 1, 64);
      float u4 = p4 + __shfl_xor(p4, 1, 64);
      float u5 = p5 + __shfl_xor(p5, 1, 64);
      float u6 = p6 + __shfl_xor(p6, 1, 64);
      float u7 = p7 + __shfl_xor(p7, 1, 64);
      float c0 = b1 ? u1 : u0;
      float c1 = b1 ? u3 : u2;
      float c2 = b1 ? u5 : u4;
      float c3 = b1 ? u7 : u6;
      float d0 = c0 + __shfl_xor(c0, 2, 64);
      float d1 = c1 + __shfl_xor(c1, 2, 64);
      float d2 = c2 + __shfl_xor(c2, 2, 64);
      float d3 = c3 + __shfl_xor(c3, 2, 64);
      float w0 = b2 ? d1 : d0;
      float w1 = b2 ? d3 : d2;
      float x0 = w0 + __shfl_xor(w0, 4, 64);
      float x1 = w1 + __shfl_xor(w1, 4, 64);
      float r = b4 ? x1 : x0;
      r += __shfl_xor(r, 8, 64);
      r += __shfl_xor(r, 16, 64);      // lane holds full logit of edge (q&7)
      float ex = __expf(r);            // one exp covers 8 edges; exp(-inf)=0
      int exi = __float_as_int(ex);
      float e0 = __int_as_float(__builtin_amdgcn_ds_bpermute(ib +  0, exi));
      float e1 = __int_as_float(__builtin_amdgcn_ds_bpermute(ib +  4, exi));
      float e2 = __int_as_float(__builtin_amdgcn_ds_bpermute(ib +  8, exi));
      float e3 = __int_as_float(__builtin_amdgcn_ds_bpermute(ib + 12, exi));
      float e4 = __int_as_float(__builtin_amdgcn_ds_bpermute(ib + 16, exi));
      float e5 = __int_as_float(__builtin_amdgcn_ds_bpermute(ib + 20, exi));
      float e6 = __int_as_float(__builtin_amdgcn_ds_bpermute(ib + 24, exi));
      float e7 = __int_as_float(__builtin_amdgcn_ds_bpermute(ib + 28, exi));
      l += ((e0 + e1) + (e2 + e3)) + ((e4 + e5) + (e6 + e7));
      acc.x = fmaf(e0, fa0.x, acc.x); acc.x = fmaf(e1, fa1.x, acc.x);
      acc.x = fmaf(e2, fa2.x, acc.x); acc.x = fmaf(e3, fa3.x, acc.x);
      acc.x = fmaf(e4, fb0.x, acc.x); acc.x = fmaf(e5, fb1.x, acc.x);
      acc.x = fmaf(e6, fb2.x, acc.x); acc.x = fmaf(e7, fb3.x, acc.x);
      acc.y = fmaf(e0, fa0.y, acc.y); acc.y = fmaf(e1, fa1.y, acc.y);
      acc.y = fmaf(e2, fa2.y, acc.y); acc.y = fmaf(e3, fa3.y, acc.y);
      acc.y = fmaf(e4, fb0.y, acc.y); acc.y = fmaf(e5, fb1.y, acc.y);
      acc.y = fmaf(e6, fb2.y, acc.y); acc.y = fmaf(e7, fb3.y, acc.y);
      acc.z = fmaf(e0, fa0.z, acc.z); acc.z = fmaf(e1, fa1.z, acc.z);
      acc.z = fmaf(e2, fa2.z, acc.z); acc.z = fmaf(e3, fa3.z, acc.z);
      acc.z = fmaf(e4, fb0.z, acc.z); acc.z = fmaf(e5, fb1.z, acc.z);
      acc.z = fmaf(e6, fb2.z, acc.z); acc.z = fmaf(e7, fb3.z, acc.z);
      acc.w = fmaf(e0, fa0.w, acc.w); acc.w = fmaf(e1, fa1.w, acc.w);
      acc.w = fmaf(e2, fa2.w, acc.w); acc.w = fmaf(e3, fa3.w, acc.w);
      acc.w = fmaf(e4, fb0.w, acc.w); acc.w = fmaf(e5, fb1.w, acc.w);
      acc.w = fmaf(e6, fb2.w, acc.w); acc.w = fmaf(e7, fb3.w, acc.w);
    }
    float inv = (l > 0.f) ? 1.f / l : 0.f;
    acc.x *= inv; acc.y *= inv; acc.z *= inv; acc.w *= inv;
    ((h4pack*)Hout)[(size_t)node * 32 + q] = f4toh4(acc);
  }
}

// ---------------- classifier: out[N,16] = H(fp16) @ cls_w ------------------
__global__ __launch_bounds__(256) void classify_kernel(
    const __half* __restrict__ H, const float* __restrict__ Wc,
    float* __restrict__ out, int N) {
  __shared__ float sW[HID * 16];     // 8 KB
  __shared__ float sH[16][132];      // padded
  for (int i = threadIdx.x; i < HID * 16; i += 256) sW[i] = Wc[i];
  int row0 = blockIdx.x * 16;
  for (int i = threadIdx.x; i < 16 * 32; i += 256) {
    int r = i >> 5, j = i & 31;
    int row = row0 + r;
    float4 v = make_float4(0.f, 0.f, 0.f, 0.f);
    if (row < N) v = h4tof4(((const h4pack*)H)[(size_t)row * 32 + j]);
    ((float4*)&sH[r][0])[j] = v;
  }
  __syncthreads();
  int r = threadIdx.x >> 4;
  int c = threadIdx.x & 15;
  float acc = 0.f;
#pragma unroll 8
  for (int k = 0; k < HID; ++k) acc = fmaf(sH[r][k], sW[k * 16 + c], acc);
  int row = row0 + r;
  if (row < N) out[(size_t)row * 16 + c] = acc;
}

// ---------------------------------------------------------------------------
extern "C" void kernel_launch(void* const* d_in, const int* in_sizes, int n_in,
                              void* d_out, int out_size, void* d_ws, size_t ws_size,
                              hipStream_t stream) {
  const int* feats     = (const int*)d_in[0];
  const int* src       = (const int*)d_in[1];
  const int* dst       = (const int*)d_in[2];
  const float* key_emb = (const float*)d_in[3];
  const float* val_emb = (const float*)d_in[4];
  const float* W1      = (const float*)d_in[5];
  const float* attn1   = (const float*)d_in[6];
  const float* W2      = (const float*)d_in[7];
  const float* attn2   = (const float*)d_in[8];
  const float* cls_w   = (const float*)d_in[9];

  int N = in_sizes[0] / 2;
  int E = in_sizes[1];
  int NB = (N + 255) / 256;

  // 16B-aligned workspace layout
  int Np = (N + 3) & ~3;
  int Ep = (E + 3) & ~3;
  char* ws = (char*)d_ws;
  __half* fbuf  = (__half*)ws;                            // Np*128 fp16
  __half* hbuf  = (__half*)(ws + (size_t)Np * HID * 2);   // Np*128 fp16
  __half* ebuf  = (__half*)(ws + (size_t)Np * HID * 4);   // Np*128 fp16 (h0)
  __half* Wt1   = (__half*)(ws + (size_t)Np * HID * 6);   // 128*128 fp16
  __half* Wt2   = Wt1 + HID * HID;                        // 128*128 fp16
  int* counts   = (int*)(Wt2 + HID * HID);                // Np
  int* offs     = counts + Np;                            // Np+4
  int* rank     = offs + Np + 4;                          // Ep
  int* csr      = rank + Ep;                              // Ep + 8*Np (8-padded)
  int* partials = csr + Ep + 8 * (size_t)Np;              // 256
  int* bases    = partials + 256;                         // 256

  zero_kernel<<<(Np / 4 + 255) / 256, 256, 0, stream>>>((int4*)counts, Np / 4);

  hist_kernel<<<(E + 255) / 256, 256, 0, stream>>>(dst, counts, rank, E);
  partial_kernel<<<NB, 256, 0, stream>>>(counts, partials, N);
  scan2_kernel<<<1, 256, 0, stream>>>(partials, bases, NB);
  offs_kernel<<<NB, 256, 0, stream>>>(counts, bases, offs, csr, N);
  scatter_kernel<<<(E + 255) / 256, 256, 0, stream>>>(src, dst, offs, rank, csr, E);

  wprep_kernel<<<64, 256, 0, stream>>>(W1, Wt1);
  wprep_kernel<<<64, 256, 0, stream>>>(W2, Wt2);
  embed_kernel<<<((size_t)N * 16 + 255) / 256, 256, 0, stream>>>(
      feats, key_emb, val_emb, ebuf, N);

  int gblocks = (N + 63) / 64;
  int gatblocks = 2048;               // 8 blocks/CU resident; grid-stride sweep
  // layer 1
  gemm_mfma_kernel<<<gblocks, 256, 0, stream>>>(ebuf, Wt1, fbuf, N);
  gat_kernel<<<gatblocks, 256, 0, stream>>>(
      fbuf, offs, counts, csr, attn1, hbuf, N);
  // layer 2
  gemm_mfma_kernel<<<gblocks, 256, 0, stream>>>(hbuf, Wt2, fbuf, N);
  gat_kernel<<<gatblocks, 256, 0, stream>>>(
      fbuf, offs, counts, csr, attn2, hbuf, N);

  classify_kernel<<<(N + 15) / 16, 256, 0, stream>>>(hbuf, cls_w, (float*)d_out, N);
}

// Round 17
// 211.706 us; speedup vs baseline: 1.0281x; 1.0281x over previous
//
#include <hip/hip_runtime.h>
#include <hip/hip_fp16.h>
#include <math.h>

#define HID 128

typedef _Float16 half8 __attribute__((ext_vector_type(8)));
typedef float floatx4 __attribute__((ext_vector_type(4)));

// 8-byte packed 4x fp16
struct h4pack { __half2 a, b; };

__device__ __forceinline__ float4 h4tof4(h4pack h) {
  float2 lo = __half22float2(h.a);
  float2 hi = __half22float2(h.b);
  return make_float4(lo.x, lo.y, hi.x, hi.y);
}

__device__ __forceinline__ h4pack f4toh4(float4 v) {
  h4pack h;
  h.a = __floats2half2_rn(v.x, v.y);
  h.b = __floats2half2_rn(v.z, v.w);
  return h;
}

// 16B of fp16 (8 dims) -> two float4
__device__ __forceinline__ void cvt8(uint4 r, float4& lo, float4& hi) {
  const h4pack* hp = (const h4pack*)&r;
  lo = h4tof4(hp[0]);
  hi = h4tof4(hp[1]);
}

// ---------------- zero workspace --------------------------------------------
__global__ __launch_bounds__(256) void zero_kernel(int4* __restrict__ p, int n4) {
  int i = blockIdx.x * 256 + threadIdx.x;
  if (i < n4) p[i] = make_int4(0, 0, 0, 0);
}

// ---------------- CSR build (padded to 8-edge octets) ------------------------
__global__ __launch_bounds__(256) void hist_kernel(
    const int* __restrict__ dst, int* __restrict__ counts,
    int* __restrict__ rank, int E) {
  int e = blockIdx.x * 256 + threadIdx.x;
  if (e < E) rank[e] = atomicAdd(&counts[dst[e]], 1);
}

__global__ __launch_bounds__(256) void partial_kernel(
    const int* __restrict__ counts, int* __restrict__ partials, int N) {
  __shared__ int s[256];
  int idx = blockIdx.x * 256 + threadIdx.x;
  int c = (idx < N) ? counts[idx] : 0;
  s[threadIdx.x] = (idx < N) ? ((c + 7) & ~7) : 0;
  __syncthreads();
  for (int o = 128; o > 0; o >>= 1) {
    if (threadIdx.x < o) s[threadIdx.x] += s[threadIdx.x + o];
    __syncthreads();
  }
  if (threadIdx.x == 0) partials[blockIdx.x] = s[0];
}

__global__ __launch_bounds__(256) void scan2_kernel(
    const int* __restrict__ partials, int* __restrict__ bases, int NB) {
  __shared__ int s[256];
  int t = threadIdx.x;
  int v0 = (t < NB) ? partials[t] : 0;
  s[t] = v0;
  __syncthreads();
  for (int o = 1; o < 256; o <<= 1) {
    int v = (t >= o) ? s[t - o] : 0;
    __syncthreads();
    s[t] += v;
    __syncthreads();
  }
  bases[t] = s[t] - v0;   // exclusive
}

__global__ __launch_bounds__(256) void offs_kernel(
    const int* __restrict__ counts, const int* __restrict__ bases,
    int* __restrict__ offs, int* __restrict__ csr, int N) {
  __shared__ int s[256];
  int t = threadIdx.x;
  int idx = blockIdx.x * 256 + t;
  int deg = (idx < N) ? counts[idx] : 0;
  int c = (idx < N) ? ((deg + 7) & ~7) : 0;
  s[t] = c;
  __syncthreads();
  for (int o = 1; o < 256; o <<= 1) {
    int v = (t >= o) ? s[t - o] : 0;
    __syncthreads();
    s[t] += v;
    __syncthreads();
  }
  int base = bases[blockIdx.x];
  if (idx < N) {
    int o = base + s[t] - c;
    offs[idx] = o;
    for (int k = deg; k < c; ++k) csr[o + k] = 0;
  }
  if (idx == N - 1) offs[N] = base + s[t];
}

__global__ __launch_bounds__(256) void scatter_kernel(
    const int* __restrict__ src, const int* __restrict__ dst,
    const int* __restrict__ offs, const int* __restrict__ rank,
    int* __restrict__ csr, int E) {
  int e = blockIdx.x * 256 + threadIdx.x;
  if (e >= E) return;
  csr[offs[dst[e]] + rank[e]] = src[e];
}

// ---------------- embed: h0 = relu(ke[f0]+ve[f1]) -> fp16 -------------------
__global__ __launch_bounds__(256) void embed_kernel(
    const int* __restrict__ feats, const float* __restrict__ ke,
    const float* __restrict__ ve, __half* __restrict__ h0, int N) {
  int gid = blockIdx.x * 256 + threadIdx.x;
  int n = gid >> 4, j = gid & 15;     // 16 threads/node, 8 dims each
  if (n >= N) return;
  int f0 = feats[2 * n], f1 = feats[2 * n + 1];
  const float4* a4 = (const float4*)(ke + (size_t)f0 * HID) + j * 2;
  const float4* b4 = (const float4*)(ve + (size_t)f1 * HID) + j * 2;
  float4 a0 = a4[0], a1 = a4[1], b0 = b4[0], b1 = b4[1];
  float4 v0, v1;
  v0.x = fmaxf(a0.x + b0.x, 0.f); v0.y = fmaxf(a0.y + b0.y, 0.f);
  v0.z = fmaxf(a0.z + b0.z, 0.f); v0.w = fmaxf(a0.w + b0.w, 0.f);
  v1.x = fmaxf(a1.x + b1.x, 0.f); v1.y = fmaxf(a1.y + b1.y, 0.f);
  v1.z = fmaxf(a1.z + b1.z, 0.f); v1.w = fmaxf(a1.w + b1.w, 0.f);
  h4pack* out = (h4pack*)h0 + (size_t)n * 32 + j * 2;
  out[0] = f4toh4(v0);
  out[1] = f4toh4(v1);
}

// ---------------- W prep: Wt[c][k] = fp16(W[k][c]) --------------------------
__global__ __launch_bounds__(256) void wprep_kernel(
    const float* __restrict__ W, __half* __restrict__ Wt) {
  int t = blockIdx.x * 256 + threadIdx.x;   // 16384
  int k = t >> 7, c = t & 127;
  Wt[(size_t)c * HID + k] = __float2half(W[t]);
}

// ---------------- GEMM via MFMA: F[N,128](fp16) = A[N,128](fp16) @ W --------
__global__ __launch_bounds__(256) void gemm_mfma_kernel(
    const __half* __restrict__ A, const __half* __restrict__ Wt,
    __half* __restrict__ F, int N) {
  int w = threadIdx.x >> 6;
  int lane = threadIdx.x & 63;
  int r = lane & 15, g = lane >> 4;
  int row0 = blockIdx.x * 64 + w * 16;
  if (row0 >= N) return;
  int arow = row0 + r;
  if (arow >= N) arow = N - 1;        // clamp (stores are guarded)
  const half8* Ap = (const half8*)(A + (size_t)arow * HID + g * 8);
  half8 a0 = Ap[0];
  half8 a1 = Ap[4];
  half8 a2 = Ap[8];
  half8 a3 = Ap[12];
#pragma unroll
  for (int ct = 0; ct < 8; ++ct) {
    const half8* Bp = (const half8*)(Wt + (size_t)(ct * 16 + r) * HID + g * 8);
    half8 b0 = Bp[0], b1 = Bp[4], b2 = Bp[8], b3 = Bp[12];
    floatx4 c = {0.f, 0.f, 0.f, 0.f};
    c = __builtin_amdgcn_mfma_f32_16x16x32_f16(a0, b0, c, 0, 0, 0);
    c = __builtin_amdgcn_mfma_f32_16x16x32_f16(a1, b1, c, 0, 0, 0);
    c = __builtin_amdgcn_mfma_f32_16x16x32_f16(a2, b2, c, 0, 0, 0);
    c = __builtin_amdgcn_mfma_f32_16x16x32_f16(a3, b3, c, 0, 0, 0);
    int col = ct * 16 + r;
#pragma unroll
    for (int reg = 0; reg < 4; ++reg) {
      int row = row0 + g * 4 + reg;
      if (row < N) F[(size_t)row * HID + col] = __float2half(c[reg]);
    }
  }
}

// ---------------- GATv2 layer (16-lane groups, 8-wide, no-max) --------------
// 16-lane group = 1 node (4 nodes/wave, 16 nodes/block); lane holds dims
// 8q..8q+8 (one 16B fp16 load per edge -> 1KB/instruction full coalescing,
// 2x bytes-in-flight vs 32-lane shape). 8 edges/iter (CSR padded to 8);
// 4-stage packed butterfly (masks<=8, within group); one exp per 8 edges
// (shift-invariant softmax, logits O(1)); bpermute broadcast (own-group base).
// Raw fp16 kept in regs; reconverted for the accumulate (saves 32 VGPR).
__device__ __forceinline__ float dot8f(uint4 raw, const float4& fd0, const float4& fd1,
                                       const float4& av0, const float4& av1) {
  float4 lo, hi;
  cvt8(raw, lo, hi);
  float t, pa = 0.f, pb = 0.f;
  t = lo.x + fd0.x; pa = fmaf(av0.x, t, pa); pb = fmaf(av0.x, fabsf(t), pb);
  t = lo.y + fd0.y; pa = fmaf(av0.y, t, pa); pb = fmaf(av0.y, fabsf(t), pb);
  t = lo.z + fd0.z; pa = fmaf(av0.z, t, pa); pb = fmaf(av0.z, fabsf(t), pb);
  t = lo.w + fd0.w; pa = fmaf(av0.w, t, pa); pb = fmaf(av0.w, fabsf(t), pb);
  t = hi.x + fd1.x; pa = fmaf(av1.x, t, pa); pb = fmaf(av1.x, fabsf(t), pb);
  t = hi.y + fd1.y; pa = fmaf(av1.y, t, pa); pb = fmaf(av1.y, fabsf(t), pb);
  t = hi.z + fd1.z; pa = fmaf(av1.z, t, pa); pb = fmaf(av1.z, fabsf(t), pb);
  t = hi.w + fd1.w; pa = fmaf(av1.w, t, pa); pb = fmaf(av1.w, fabsf(t), pb);
  return 0.6f * pa + 0.4f * pb;
}

__global__ __launch_bounds__(256) void gat_kernel(
    const __half* __restrict__ F, const int* __restrict__ offs,
    const int* __restrict__ counts, const int* __restrict__ csr,
    const float* __restrict__ attn, __half* __restrict__ Hout, int N) {
  int node = blockIdx.x * 16 + (threadIdx.x >> 4);
  if (node >= N) return;
  int q = threadIdx.x & 15;
  int lane = threadIdx.x & 63;
  const uint4* F16 = (const uint4*)F;   // row = 16 uint4
  float4 fd0, fd1;
  cvt8(F16[(size_t)node * 16 + q], fd0, fd1);
  float4 av0 = ((const float4*)attn)[q * 2];
  float4 av1 = ((const float4*)attn)[q * 2 + 1];
  int ib = (lane & 48) << 2;            // bpermute byte base of this group
  bool b1 = (q & 1) != 0;
  bool b2 = (q & 2) != 0;
  bool b4 = (q & 4) != 0;

  int beg = offs[node];
  int cnt = counts[node];
  float l = 0.f;
  float4 acc0 = make_float4(0.f, 0.f, 0.f, 0.f), acc1 = acc0;

  int nit = (cnt + 7) >> 3;
  const int* cp = csr + beg;            // beg multiple of 8 -> 32B aligned
  for (int it = 0; it < nit; ++it) {
    const int4* qp = (const int4*)(cp + 8 * it);
    int4 sa = qp[0];
    int4 sb = qp[1];
    uint4 r0 = F16[(size_t)sa.x * 16 + q];
    uint4 r1 = F16[(size_t)sa.y * 16 + q];
    uint4 r2 = F16[(size_t)sa.z * 16 + q];
    uint4 r3 = F16[(size_t)sa.w * 16 + q];
    uint4 r4 = F16[(size_t)sb.x * 16 + q];
    uint4 r5 = F16[(size_t)sb.y * 16 + q];
    uint4 r6 = F16[(size_t)sb.z * 16 + q];
    uint4 r7 = F16[(size_t)sb.w * 16 + q];
    int rem = cnt - 8 * it;
    float p0 = dot8f(r0, fd0, fd1, av0, av1);
    float p1 = (1 < rem) ? dot8f(r1, fd0, fd1, av0, av1) : -INFINITY;
    float p2 = (2 < rem) ? dot8f(r2, fd0, fd1, av0, av1) : -INFINITY;
    float p3 = (3 < rem) ? dot8f(r3, fd0, fd1, av0, av1) : -INFINITY;
    float p4 = (4 < rem) ? dot8f(r4, fd0, fd1, av0, av1) : -INFINITY;
    float p5 = (5 < rem) ? dot8f(r5, fd0, fd1, av0, av1) : -INFINITY;
    float p6 = (6 < rem) ? dot8f(r6, fd0, fd1, av0, av1) : -INFINITY;
    float p7 = (7 < rem) ? dot8f(r7, fd0, fd1, av0, av1) : -INFINITY;
    // 4-stage packed butterfly within the 16-lane group (masks <= 8)
    float u0 = p0 + __shfl_xor(p0, 1, 64);
    float u1 = p1 + __shfl_xor(p1, 1, 64);
    float u2 = p2 + __shfl_xor(p2, 1, 64);
    float u3 = p3 + __shfl_xor(p3, 1, 64);
    float u4 = p4 + __shfl_xor(p4, 1, 64);
    float u5 = p5 + __shfl_xor(p5, 1, 64);
    float u6 = p6 + __shfl_xor(p6, 1, 64);
    float u7 = p7 + __shfl_xor(p7, 1, 64);
    float c0 = b1 ? u1 : u0;
    float c1 = b1 ? u3 : u2;
    float c2 = b1 ? u5 : u4;
    float c3 = b1 ? u7 : u6;
    float d0 = c0 + __shfl_xor(c0, 2, 64);
    float d1 = c1 + __shfl_xor(c1, 2, 64);
    float d2 = c2 + __shfl_xor(c2, 2, 64);
    float d3 = c3 + __shfl_xor(c3, 2, 64);
    float e0s = b2 ? d1 : d0;
    float e1s = b2 ? d3 : d2;
    float f0s = e0s + __shfl_xor(e0s, 4, 64);
    float f1s = e1s + __shfl_xor(e1s, 4, 64);
    float g = b4 ? f1s : f0s;
    float r = g + __shfl_xor(g, 8, 64);   // lane holds full logit of edge (q&7)
    float ex = __expf(r);                 // one exp covers 8 edges; exp(-inf)=0
    int exi = __float_as_int(ex);
    float e0 = __int_as_float(__builtin_amdgcn_ds_bpermute(ib +  0, exi));
    float e1 = __int_as_float(__builtin_amdgcn_ds_bpermute(ib +  4, exi));
    float e2 = __int_as_float(__builtin_amdgcn_ds_bpermute(ib +  8, exi));
    float e3 = __int_as_float(__builtin_amdgcn_ds_bpermute(ib + 12, exi));
    float e4 = __int_as_float(__builtin_amdgcn_ds_bpermute(ib + 16, exi));
    float e5 = __int_as_float(__builtin_amdgcn_ds_bpermute(ib + 20, exi));
    float e6 = __int_as_float(__builtin_amdgcn_ds_bpermute(ib + 24, exi));
    float e7 = __int_as_float(__builtin_amdgcn_ds_bpermute(ib + 28, exi));
    l += ((e0 + e1) + (e2 + e3)) + ((e4 + e5) + (e6 + e7));
    float4 lo, hi;
#define ACC_EDGE(RAW, EV)                                                      \
    cvt8(RAW, lo, hi);                                                         \
    acc0.x = fmaf(EV, lo.x, acc0.x); acc0.y = fmaf(EV, lo.y, acc0.y);          \
    acc0.z = fmaf(EV, lo.z, acc0.z); acc0.w = fmaf(EV, lo.w, acc0.w);          \
    acc1.x = fmaf(EV, hi.x, acc1.x); acc1.y = fmaf(EV, hi.y, acc1.y);          \
    acc1.z = fmaf(EV, hi.z, acc1.z); acc1.w = fmaf(EV, hi.w, acc1.w);
    ACC_EDGE(r0, e0) ACC_EDGE(r1, e1) ACC_EDGE(r2, e2) ACC_EDGE(r3, e3)
    ACC_EDGE(r4, e4) ACC_EDGE(r5, e5) ACC_EDGE(r6, e6) ACC_EDGE(r7, e7)
#undef ACC_EDGE
  }
  float inv = (l > 0.f) ? 1.f / l : 0.f;
  acc0.x *= inv; acc0.y *= inv; acc0.z *= inv; acc0.w *= inv;
  acc1.x *= inv; acc1.y *= inv; acc1.z *= inv; acc1.w *= inv;
  h4pack o0 = f4toh4(acc0), o1 = f4toh4(acc1);
  uint4 ov;
  h4pack* op = (h4pack*)&ov;
  op[0] = o0; op[1] = o1;
  ((uint4*)Hout)[(size_t)node * 16 + q] = ov;
}

// ---------------- classifier: out[N,16] = H(fp16) @ cls_w ------------------
__global__ __launch_bounds__(256) void classify_kernel(
    const __half* __restrict__ H, const float* __restrict__ Wc,
    float* __restrict__ out, int N) {
  __shared__ float sW[HID * 16];     // 8 KB
  __shared__ float sH[16][132];      // padded
  for (int i = threadIdx.x; i < HID * 16; i += 256) sW[i] = Wc[i];
  int row0 = blockIdx.x * 16;
  for (int i = threadIdx.x; i < 16 * 32; i += 256) {
    int r = i >> 5, j = i & 31;
    int row = row0 + r;
    float4 v = make_float4(0.f, 0.f, 0.f, 0.f);
    if (row < N) v = h4tof4(((const h4pack*)H)[(size_t)row * 32 + j]);
    ((float4*)&sH[r][0])[j] = v;
  }
  __syncthreads();
  int r = threadIdx.x >> 4;
  int c = threadIdx.x & 15;
  float acc = 0.f;
#pragma unroll 8
  for (int k = 0; k < HID; ++k) acc = fmaf(sH[r][k], sW[k * 16 + c], acc);
  int row = row0 + r;
  if (row < N) out[(size_t)row * 16 + c] = acc;
}

// ---------------------------------------------------------------------------
extern "C" void kernel_launch(void* const* d_in, const int* in_sizes, int n_in,
                              void* d_out, int out_size, void* d_ws, size_t ws_size,
                              hipStream_t stream) {
  const int* feats     = (const int*)d_in[0];
  const int* src       = (const int*)d_in[1];
  const int* dst       = (const int*)d_in[2];
  const float* key_emb = (const float*)d_in[3];
  const float* val_emb = (const float*)d_in[4];
  const float* W1      = (const float*)d_in[5];
  const float* attn1   = (const float*)d_in[6];
  const float* W2      = (const float*)d_in[7];
  const float* attn2   = (const float*)d_in[8];
  const float* cls_w   = (const float*)d_in[9];

  int N = in_sizes[0] / 2;
  int E = in_sizes[1];
  int NB = (N + 255) / 256;

  // 16B-aligned workspace layout
  int Np = (N + 3) & ~3;
  int Ep = (E + 3) & ~3;
  char* ws = (char*)d_ws;
  __half* fbuf  = (__half*)ws;                            // Np*128 fp16
  __half* hbuf  = (__half*)(ws + (size_t)Np * HID * 2);   // Np*128 fp16
  __half* ebuf  = (__half*)(ws + (size_t)Np * HID * 4);   // Np*128 fp16 (h0)
  __half* Wt1   = (__half*)(ws + (size_t)Np * HID * 6);   // 128*128 fp16
  __half* Wt2   = Wt1 + HID * HID;                        // 128*128 fp16
  int* counts   = (int*)(Wt2 + HID * HID);                // Np
  int* offs     = counts + Np;                            // Np+4
  int* rank     = offs + Np + 4;                          // Ep
  int* csr      = rank + Ep;                              // Ep + 8*Np (8-padded)
  int* partials = csr + Ep + 8 * (size_t)Np;              // 256
  int* bases    = partials + 256;                         // 256

  zero_kernel<<<(Np / 4 + 255) / 256, 256, 0, stream>>>((int4*)counts, Np / 4);

  hist_kernel<<<(E + 255) / 256, 256, 0, stream>>>(dst, counts, rank, E);
  partial_kernel<<<NB, 256, 0, stream>>>(counts, partials, N);
  scan2_kernel<<<1, 256, 0, stream>>>(partials, bases, NB);
  offs_kernel<<<NB, 256, 0, stream>>>(counts, bases, offs, csr, N);
  scatter_kernel<<<(E + 255) / 256, 256, 0, stream>>>(src, dst, offs, rank, csr, E);

  wprep_kernel<<<64, 256, 0, stream>>>(W1, Wt1);
  wprep_kernel<<<64, 256, 0, stream>>>(W2, Wt2);
  embed_kernel<<<((size_t)N * 16 + 255) / 256, 256, 0, stream>>>(
      feats, key_emb, val_emb, ebuf, N);

  int gblocks = (N + 63) / 64;
  int gatblocks = (N + 15) / 16;      // many small blocks: scheduler backfills
  // layer 1
  gemm_mfma_kernel<<<gblocks, 256, 0, stream>>>(ebuf, Wt1, fbuf, N);
  gat_kernel<<<gatblocks, 256, 0, stream>>>(
      fbuf, offs, counts, csr, attn1, hbuf, N);
  // layer 2
  gemm_mfma_kernel<<<gblocks, 256, 0, stream>>>(hbuf, Wt2, fbuf, N);
  gat_kernel<<<gatblocks, 256, 0, stream>>>(
      fbuf, offs, counts, csr, attn2, hbuf, N);

  classify_kernel<<<(N + 15) / 16, 256, 0, stream>>>(hbuf, cls_w, (float*)d_out, N);
}